// Round 6
// baseline (582.044 us; speedup 1.0000x reference)
//
#include <hip/hip_runtime.h>

// ---------------------------------------------------------------------------
// PointTransformerBlock, MI355X.  R18 = R17 + software-pipelined k_edge:
//  R17 falsified "VALU-bound": occupancy 30->39% + fewer VALU gave dur
//  unchanged (184us), VALUBusy DOWN.  k_edge is LATENCY-bound on the
//  per-tile gather chain (spair -> pos/q/k/v HBM-miss gathers consumed
//  within ~0-500cy; FETCH=7x working set from cross-XCD refetch).
//  Fix (guide T14): manual 2x-unrolled tile loop with explicit A/B register
//  double buffers (static indexing).  Each phase issues the NEXT tile's
//  q/k/v/pos RAW loads (pos subtraction deferred to use) + pair two tiles
//  ahead, then computes the current tile from regs loaded a full phase
//  (~1500-2000cy) earlier -- covers the ~900cy miss latency entirely.
//  VGPR ~64+32 buffer < 128 cap (launch_bounds(256,4)) -> occupancy kept.
//  - LDS 38.9KB (4 blocks/CU), an_W2 in regs, pay-fused SD (R17).
//  MFMA layouts (HW-verified, guide §3): A[m=lane&15][k=q*8+j],
//  B[k=q*8+j][n=lane&15], C/D col=lane&15 row=q*4+r.
// ---------------------------------------------------------------------------

typedef __bf16 bf16x8 __attribute__((ext_vector_type(8)));
typedef float f32x4 __attribute__((ext_vector_type(4)));

__device__ inline unsigned short f2bf(float f) {
  return __builtin_bit_cast(unsigned short, (__bf16)f);   // v_cvt (RNE)
}
__device__ inline float bf2f(unsigned short s) {
  return __uint_as_float(((unsigned int)s) << 16);
}
__device__ inline bf16x8 ld_bf8(const unsigned short* p) {
  union { uint4 i; bf16x8 v; } u;
  u.i = *(const uint4*)p;
  return u.v;
}
// packed f32->2xbf16 (gfx950; no builtin -- guide T12/m240). dst.lo=cvt(lo).
__device__ inline unsigned int cvt_pk_bf16(float lo, float hi) {
  unsigned int r;
  asm("v_cvt_pk_bf16_f32 %0, %1, %2" : "=v"(r) : "v"(lo), "v"(hi));
  return r;
}

// --------------------- prep kernel with fused histogram --------------------

__global__ __launch_bounds__(256) void k_prep_hist(
    const float* __restrict__ W_in, const float* __restrict__ W_dst,
    const float* __restrict__ W_src, const float* __restrict__ W_lin,
    const float* __restrict__ pn_W2, const float* __restrict__ an_W1,
    const float* __restrict__ an_W2, const float* __restrict__ W_out,
    unsigned short* __restrict__ wt,
    const int* __restrict__ dst, int* __restrict__ hist, int E) {
  int t = threadIdx.x;
  if (blockIdx.x >= 8) {
    int e = (blockIdx.x - 8) * 256 + t;
    if (e < E) atomicAdd(&hist[dst[e]], 1);
    return;
  }
  const float* Ws[8] = {W_in, W_dst, W_src, W_lin, pn_W2, an_W1, an_W2, W_out};
  const float* W = Ws[blockIdx.x];
  unsigned short* o = wt + (size_t)blockIdx.x * 4608;
#pragma unroll
  for (int i = 0; i < 16; ++i) {
    int e = i * 256 + t;           // e = k*64 + n  (coalesced read)
    int k = e >> 6, n = e & 63;
    o[n * 72 + k] = f2bf(W[e]);    // wt[n][k] = W^T[n][k]
  }
}

// ------------------------------ sort kernels -------------------------------

// scan3 with inline block-offset: reduce bsum[0..blockIdx) in-block.
// Requires gridDim <= 256 (N <= 262144).
__global__ __launch_bounds__(256) void k_scan3(
    const int* __restrict__ incl, const int* __restrict__ hist,
    const int* __restrict__ bsum, int* __restrict__ cursor, int N) {
  __shared__ int red[256];
  int t = threadIdx.x;
  red[t] = (t < (int)blockIdx.x) ? bsum[t] : 0;
  __syncthreads();
#pragma unroll
  for (int off = 128; off; off >>= 1) {
    if (t < off) red[t] += red[t + off];
    __syncthreads();
  }
  int bo = red[0];
  int base = blockIdx.x * 1024 + t * 4;
#pragma unroll
  for (int i = 0; i < 4; ++i) {
    int id = base + i;
    if (id < N) cursor[id] = bo + incl[id] - hist[id];
  }
}

// scatter with fused sg/accg zeroing (sibling blocks).
__global__ void k_scatter_zero(const int* __restrict__ src,
                               const int* __restrict__ dst,
                               int* __restrict__ cursor,
                               int2* __restrict__ spair, int E,
                               float4* __restrict__ zbase, int zcount,
                               int scatterBlocks) {
  int t = threadIdx.x;
  if ((int)blockIdx.x >= scatterBlocks) {
    int i = ((int)blockIdx.x - scatterBlocks) * 256 + t;
    if (i < zcount) zbase[i] = make_float4(0.f, 0.f, 0.f, 0.f);
    return;
  }
  int e = blockIdx.x * 256 + t;
  if (e < E) {
    int s = src[e], d = dst[e];
    int p = atomicAdd(&cursor[d], 1);
    spair[p] = make_int2(s, d);
  }
}

// ---------------- node kernel (transposed MFMA) with fused scan1 -----------

__global__ __launch_bounds__(256) void k_node(
    const float* __restrict__ x, const unsigned short* __restrict__ wt,
    const float* __restrict__ b_in, const float* __restrict__ ln_g,
    const float* __restrict__ ln_b,
    unsigned short* __restrict__ qg, unsigned short* __restrict__ kg,
    unsigned short* __restrict__ vg,
    int N, const int* __restrict__ hist, int* __restrict__ incl,
    int* __restrict__ bsum, int nodeBlocks) {
  int t = threadIdx.x;

  // ---- fused scan1 blocks ----
  if ((int)blockIdx.x >= nodeBlocks) {
    __shared__ int sd[256];
    int bid = blockIdx.x - nodeBlocks;
    int base = bid * 1024 + t * 4;
    int v[4]; int ts = 0;
#pragma unroll
    for (int i = 0; i < 4; ++i) {
      int idx = base + i;
      v[i] = (idx < N) ? hist[idx] : 0;
      ts += v[i];
    }
    sd[t] = ts;
    __syncthreads();
    for (int off = 1; off < 256; off <<= 1) {
      int xv = (t >= off) ? sd[t - off] : 0;
      __syncthreads();
      sd[t] += xv;
      __syncthreads();
    }
    int run = sd[t] - ts;
#pragma unroll
    for (int i = 0; i < 4; ++i) {
      run += v[i];
      int idx = base + i;
      if (idx < N) incl[idx] = run;
    }
    if (t == 255) bsum[bid] = sd[255];
    return;
  }

  __shared__ __align__(16) unsigned short WALL[4 * 64 * 72];
  __shared__ __align__(16) unsigned short HT[64 * 72];   // h [node][ch]
  __shared__ __align__(16) float LNG[64], LNB[64], BIN[64];

  int lane = t & 63, wv = t >> 6;
  int nl = lane & 15, q = lane >> 4;
  int w16 = wv * 16;
  int n0g = blockIdx.x * 64;

  {
    const uint4* s4 = (const uint4*)wt;
    uint4* d4 = (uint4*)WALL;
#pragma unroll
    for (int i = 0; i < 9; ++i) d4[i * 256 + t] = s4[i * 256 + t];
  }
  if (t < 64) { LNG[t] = ln_g[t]; LNB[t] = ln_b[t]; BIN[t] = b_in[t]; }

  int row = n0g + w16 + nl;        // my node
  bf16x8 b[2];                     // B-frag: x[node=nl][k]
#pragma unroll
  for (int s = 0; s < 2; ++s) {
    union { unsigned int u[4]; bf16x8 v; } fb;
    if (row < N) {
      int kb = s * 32 + q * 8;
      float4 xa = *(const float4*)(x + (size_t)row * 64 + kb);
      float4 xb = *(const float4*)(x + (size_t)row * 64 + kb + 4);
      fb.u[0] = cvt_pk_bf16(xa.x, xa.y);
      fb.u[1] = cvt_pk_bf16(xa.z, xa.w);
      fb.u[2] = cvt_pk_bf16(xb.x, xb.y);
      fb.u[3] = cvt_pk_bf16(xb.z, xb.w);
    } else {
#pragma unroll
      for (int j = 0; j < 4; ++j) fb.u[j] = 0;
    }
    b[s] = fb.v;
  }
  __syncthreads();

  // GEMM1: h = relu(x @ W_in + b_in); lane holds ch m0*16+q*4+r of node nl
  f32x4 h[4];
#pragma unroll
  for (int m0 = 0; m0 < 4; ++m0) {
    f32x4 acc = *(const f32x4*)&BIN[m0 * 16 + q * 4];
    acc = __builtin_amdgcn_mfma_f32_16x16x32_bf16(
        ld_bf8(&WALL[(m0 * 16 + nl) * 72 + q * 8]), b[0], acc, 0, 0, 0);
    acc = __builtin_amdgcn_mfma_f32_16x16x32_bf16(
        ld_bf8(&WALL[(m0 * 16 + nl) * 72 + 32 + q * 8]), b[1], acc, 0, 0, 0);
#pragma unroll
    for (int r = 0; r < 4; ++r) acc[r] = fmaxf(acc[r], 0.f);
    h[m0] = acc;
  }

  // LayerNorm over channels of node nl: local 16 + reduce across q-lanes
  float sv = 0.f, sq = 0.f;
#pragma unroll
  for (int m0 = 0; m0 < 4; ++m0)
#pragma unroll
    for (int r = 0; r < 4; ++r) {
      float v = h[m0][r];
      sv += v; sq += v * v;
    }
  sv += __shfl_xor(sv, 16); sq += __shfl_xor(sq, 16);
  sv += __shfl_xor(sv, 32); sq += __shfl_xor(sq, 32);
  float mu = sv * (1.f / 64.f);
  float var = sq * (1.f / 64.f) - mu * mu;
  float rs = rsqrtf(var + 1e-5f);
#pragma unroll
  for (int m0 = 0; m0 < 4; ++m0) {
    f32x4 g4 = *(const f32x4*)&LNG[m0 * 16 + q * 4];
    f32x4 o4 = *(const f32x4*)&LNB[m0 * 16 + q * 4];
    float v0 = (h[m0][0] - mu) * rs * g4[0] + o4[0];
    float v1 = (h[m0][1] - mu) * rs * g4[1] + o4[1];
    float v2 = (h[m0][2] - mu) * rs * g4[2] + o4[2];
    float v3 = (h[m0][3] - mu) * rs * g4[3] + o4[3];
    uint2 pk;
    pk.x = cvt_pk_bf16(v0, v1);
    pk.y = cvt_pk_bf16(v2, v3);
    *(uint2*)&HT[(w16 + nl) * 72 + m0 * 16 + q * 4] = pk;
  }

  b[0] = ld_bf8(&HT[(w16 + nl) * 72 + q * 8]);
  b[1] = ld_bf8(&HT[(w16 + nl) * 72 + 32 + q * 8]);

  unsigned short* Og[3] = {qg, kg, vg};
  bool g = row < N;
#pragma unroll
  for (int m = 0; m < 3; ++m) {
    const unsigned short* Wm = WALL + (m + 1) * 4608;
#pragma unroll
    for (int m0 = 0; m0 < 4; ++m0) {
      f32x4 acc = {0.f, 0.f, 0.f, 0.f};
      acc = __builtin_amdgcn_mfma_f32_16x16x32_bf16(
          ld_bf8(&Wm[(m0 * 16 + nl) * 72 + q * 8]), b[0], acc, 0, 0, 0);
      acc = __builtin_amdgcn_mfma_f32_16x16x32_bf16(
          ld_bf8(&Wm[(m0 * 16 + nl) * 72 + 32 + q * 8]), b[1], acc, 0, 0, 0);
      if (g) {
        uint2 pk;
        pk.x = cvt_pk_bf16(acc[0], acc[1]);
        pk.y = cvt_pk_bf16(acc[2], acc[3]);
        *(uint2*)(Og[m] + (size_t)row * 64 + m0 * 16 + q * 4) = pk;
      }
    }
  }
}

// ---- edge kernel (persistent, software-pipelined A/B double buffer) -------

__global__ __launch_bounds__(256, 4) void k_edge(
    const int2* __restrict__ spair, const float* __restrict__ pos,
    const unsigned short* __restrict__ qg, const unsigned short* __restrict__ kg,
    const unsigned short* __restrict__ vg,
    const unsigned short* __restrict__ wt,
    const float* __restrict__ pn_W1, const float* __restrict__ pn_b1,
    const float* __restrict__ pn_b2,
    const float* __restrict__ an_b1, const float* __restrict__ an_b2,
    float* __restrict__ sg, float* __restrict__ accg, int E, int numTiles) {
  __shared__ __align__(16) unsigned short WAB[2 * 64 * 72];  // pn_W2 | an_W1
  __shared__ __align__(16) unsigned short SD[64 * 72];   // delta, then pay
  __shared__ __align__(16) unsigned short SB[64 * 72];   // a1, then ex
  __shared__ float W1[3 * 64];
  __shared__ float B1[64];
  __shared__ __align__(16) float B2[64], AB1[64], AB2[64];

  int t = threadIdx.x;
  int lane = t & 63, wv = t >> 6;
  int nl = lane & 15, q = lane >> 4;
  int w16 = wv * 16;

  // ---- one-time staging: pn_W2 + an_W1 to LDS (uint4 memcpy) ----
  {
    const uint4* s4 = (const uint4*)(wt + 4 * 4608);  // matrices 4,5
    uint4* d4 = (uint4*)WAB;
#pragma unroll
    for (int i = 0; i < 5; ++i) {
      int idx = i * 256 + t;
      if (idx < 1152) d4[idx] = s4[idx];
    }
  }
  if (t < 192) W1[t] = pn_W1[t];
  if (t < 64) {
    B1[t] = pn_b1[t];  B2[t] = pn_b2[t];
    AB1[t] = an_b1[t]; AB2[t] = an_b2[t];
  }
  // ---- an_W2 A-frags -> registers (32 VGPR), straight from wt ----
  bf16x8 wan2r[8];
#pragma unroll
  for (int m0 = 0; m0 < 4; ++m0)
#pragma unroll
    for (int s = 0; s < 2; ++s)
      wan2r[m0 * 2 + s] =
          ld_bf8(wt + 6 * 4608 + (m0 * 16 + nl) * 72 + s * 32 + q * 8);
  const unsigned short* WPN2 = WAB;
  const unsigned short* WAN1 = WAB + 4608;
  __syncthreads();   // the ONLY barrier: weights/biases visible to all waves

  const long stride = gridDim.x;
  const long er_off = w16 + nl;     // my edge slot within a tile

  // pair load, guarded (tile may be past the end; row 0 fallback is safe)
  auto loadPair = [&](long tile) -> int2 {
    if (tile >= numTiles) return make_int2(0, 0);
    long er = tile * 64 + er_off;
    return (er < E) ? spair[er] : make_int2(0, 0);
  };
  // issue RAW gathers for a tile (no dependent arithmetic -- T14 issue-early)
  auto issueGather = [&](const int2& my, bf16x8 (&qf)[2], bf16x8 (&kf)[2],
                         uint2 (&vcp)[4], float (&pr)[6]) {
    const unsigned short* qr = qg + (size_t)my.y * 64;
    const unsigned short* kr = kg + (size_t)my.x * 64;
#pragma unroll
    for (int s = 0; s < 2; ++s) {
      int kb = s * 32 + q * 8;
      qf[s] = ld_bf8(qr + kb);
      kf[s] = ld_bf8(kr + kb);
    }
#pragma unroll
    for (int m0 = 0; m0 < 4; ++m0)
      vcp[m0] = *(const uint2*)(vg + (size_t)my.x * 64 + m0 * 16 + q * 4);
    pr[0] = pos[my.y * 3 + 0]; pr[1] = pos[my.y * 3 + 1];
    pr[2] = pos[my.y * 3 + 2];
    pr[3] = pos[my.x * 3 + 0]; pr[4] = pos[my.x * 3 + 1];
    pr[5] = pos[my.x * 3 + 2];
  };

  // full per-tile compute (R17 body), inputs all in registers
  auto computeTile = [&](long tile, const int2& my, bf16x8 (&qf)[2],
                         bf16x8 (&kf)[2], uint2 (&vcp)[4], float (&pr)[6]) {
    long e0 = tile * 64;
    bool elive = (e0 + er_off) < E;
    float p0 = pr[0] - pr[3], p1 = pr[1] - pr[4], p2 = pr[2] - pr[5];

    bf16x8 b[2];
    // pos-MLP layer1 (K=3) straight into B-frag registers
#pragma unroll
    for (int s = 0; s < 2; ++s) {
      union { unsigned int u[4]; bf16x8 v; } fb;
      int kb = s * 32 + q * 8;
#pragma unroll
      for (int jj = 0; jj < 4; ++jj) {
        int c0 = kb + 2 * jj, c1 = c0 + 1;
        float v0 = fmaf(p0, W1[c0],
                   fmaf(p1, W1[64 + c0],
                   fmaf(p2, W1[128 + c0], B1[c0])));
        float v1 = fmaf(p0, W1[c1],
                   fmaf(p1, W1[64 + c1],
                   fmaf(p2, W1[128 + c1], B1[c1])));
        fb.u[jj] = cvt_pk_bf16(fmaxf(v0, 0.f), fmaxf(v1, 0.f));
      }
      b[s] = fb.v;
    }

    // GEMM1: delta^T = pn_W2^T @ A1^T, bias-in-acc, relu -> SD (f32 in dlt)
    f32x4 dlt[4];
#pragma unroll
    for (int m0 = 0; m0 < 4; ++m0) {
      f32x4 acc = *(const f32x4*)&B2[m0 * 16 + q * 4];
      acc = __builtin_amdgcn_mfma_f32_16x16x32_bf16(
          ld_bf8(&WPN2[(m0 * 16 + nl) * 72 + q * 8]), b[0], acc, 0, 0, 0);
      acc = __builtin_amdgcn_mfma_f32_16x16x32_bf16(
          ld_bf8(&WPN2[(m0 * 16 + nl) * 72 + 32 + q * 8]), b[1], acc, 0, 0, 0);
#pragma unroll
      for (int r = 0; r < 4; ++r) acc[r] = fmaxf(acc[r], 0.f);
      dlt[m0] = acc;
      uint2 pk;
      pk.x = cvt_pk_bf16(acc[0], acc[1]);
      pk.y = cvt_pk_bf16(acc[2], acc[3]);
      *(uint2*)&SD[(w16 + nl) * 72 + m0 * 16 + q * 4] = pk;
    }

    // build ai = q[dst]-k[src]+delta in B-frag layout (reads SD)
#pragma unroll
    for (int s = 0; s < 2; ++s) {
      int kb = s * 32 + q * 8;
      bf16x8 d8 = ld_bf8(&SD[(w16 + nl) * 72 + kb]);
      union { unsigned int u[4]; bf16x8 v; } fb;
#pragma unroll
      for (int jj = 0; jj < 4; ++jj) {
        float v0 = (float)qf[s][2 * jj]     - (float)kf[s][2 * jj]     + (float)d8[2 * jj];
        float v1 = (float)qf[s][2 * jj + 1] - (float)kf[s][2 * jj + 1] + (float)d8[2 * jj + 1];
        fb.u[jj] = cvt_pk_bf16(v0, v1);
      }
      b[s] = fb.v;
    }

    // overwrite SD with pay = delta + v[src] (same-wave DS order: safe)
#pragma unroll
    for (int m0 = 0; m0 < 4; ++m0) {
      float va0 = __uint_as_float(vcp[m0].x << 16);
      float va1 = __uint_as_float(vcp[m0].x & 0xffff0000u);
      float va2 = __uint_as_float(vcp[m0].y << 16);
      float va3 = __uint_as_float(vcp[m0].y & 0xffff0000u);
      uint2 pk;
      pk.x = cvt_pk_bf16(dlt[m0][0] + va0, dlt[m0][1] + va1);
      pk.y = cvt_pk_bf16(dlt[m0][2] + va2, dlt[m0][3] + va3);
      *(uint2*)&SD[(w16 + nl) * 72 + m0 * 16 + q * 4] = pk;
    }

    // GEMM2: a1^T = an_W1^T @ ai^T, bias-in-acc, relu -> SB
#pragma unroll
    for (int m0 = 0; m0 < 4; ++m0) {
      f32x4 acc = *(const f32x4*)&AB1[m0 * 16 + q * 4];
      acc = __builtin_amdgcn_mfma_f32_16x16x32_bf16(
          ld_bf8(&WAN1[(m0 * 16 + nl) * 72 + q * 8]), b[0], acc, 0, 0, 0);
      acc = __builtin_amdgcn_mfma_f32_16x16x32_bf16(
          ld_bf8(&WAN1[(m0 * 16 + nl) * 72 + 32 + q * 8]), b[1], acc, 0, 0, 0);
      uint2 pk;
      pk.x = cvt_pk_bf16(fmaxf(acc[0], 0.f), fmaxf(acc[1], 0.f));
      pk.y = cvt_pk_bf16(fmaxf(acc[2], 0.f), fmaxf(acc[3], 0.f));
      *(uint2*)&SB[(w16 + nl) * 72 + m0 * 16 + q * 4] = pk;
    }

    // GEMM3: alpha^T = an_W2^T(regs) @ a1^T; ex = exp(relu) -> SB
    b[0] = ld_bf8(&SB[(w16 + nl) * 72 + q * 8]);
    b[1] = ld_bf8(&SB[(w16 + nl) * 72 + 32 + q * 8]);
#pragma unroll
    for (int m0 = 0; m0 < 4; ++m0) {
      f32x4 acc = *(const f32x4*)&AB2[m0 * 16 + q * 4];
      acc = __builtin_amdgcn_mfma_f32_16x16x32_bf16(
          wan2r[m0 * 2 + 0], b[0], acc, 0, 0, 0);
      acc = __builtin_amdgcn_mfma_f32_16x16x32_bf16(
          wan2r[m0 * 2 + 1], b[1], acc, 0, 0, 0);
      float e0v = elive ? __expf(fmaxf(acc[0], 0.f)) : 0.f;
      float e1v = elive ? __expf(fmaxf(acc[1], 0.f)) : 0.f;
      float e2v = elive ? __expf(fmaxf(acc[2], 0.f)) : 0.f;
      float e3v = elive ? __expf(fmaxf(acc[3], 0.f)) : 0.f;
      uint2 pk;
      pk.x = cvt_pk_bf16(e0v, e1v);
      pk.y = cvt_pk_bf16(e2v, e3v);
      *(uint2*)&SB[(w16 + nl) * 72 + m0 * 16 + q * 4] = pk;
    }

    // segmented per-dst-run reduction (dst runs via shuffle)
    {
      int c = lane;
      int cur = __shfl(my.y, 0);
      float ssum = 0.f, asum = 0.f;
#pragma unroll
      for (int i = 0; i < 16; ++i) {
        int d = __shfl(my.y, i);
        if (d != cur) {
          if (ssum != 0.f) {
            atomicAdd(&sg[(size_t)cur * 64 + c], ssum);
            atomicAdd(&accg[(size_t)cur * 64 + c], asum);
          }
          cur = d; ssum = 0.f; asum = 0.f;
        }
        float ex = bf2f(SB[(w16 + i) * 72 + c]);
        float pay = bf2f(SD[(w16 + i) * 72 + c]);   // pay = delta + v
        ssum += ex;
        asum = fmaf(ex, pay, asum);
      }
      if (ssum != 0.f) {
        atomicAdd(&sg[(size_t)cur * 64 + c], ssum);
        atomicAdd(&accg[(size_t)cur * 64 + c], asum);
      }
    }
  };

  // ---- pipeline: A/B register double buffers, 2x-unrolled loop ----
  int2 myA, myB;
  bf16x8 qfA[2], kfA[2], qfB[2], kfB[2];
  uint2 vcpA[4], vcpB[4];
  float prA[6], prB[6];

  long tile0 = blockIdx.x;
  myA = loadPair(tile0);
  issueGather(myA, qfA, kfA, vcpA, prA);   // one-time serial hop
  myB = loadPair(tile0 + stride);

  for (long tile = tile0; tile < numTiles; tile += 2 * stride) {
    // Phase A: prefetch tile+stride into B; pair for tile+2*stride; compute A
    issueGather(myB, qfB, kfB, vcpB, prB);
    int2 myA2 = loadPair(tile + 2 * stride);
    computeTile(tile, myA, qfA, kfA, vcpA, prA);
    myA = myA2;
    // Phase B: prefetch tile+2*stride into A; pair for tile+3*stride; compute B
    if (tile + stride < numTiles) {
      issueGather(myA, qfA, kfA, vcpA, prA);
      int2 myB2 = loadPair(tile + 3 * stride);
      computeTile(tile + stride, myB, qfB, kfB, vcpB, prB);
      myB = myB2;
    }
  }
}

// ------------------------- out kernel (transposed MFMA) --------------------

__global__ __launch_bounds__(256) void k_out(const float* __restrict__ accg,
                                             const float* __restrict__ sg,
                                             const unsigned short* __restrict__ wt,
                                             const float* __restrict__ b,
                                             float* __restrict__ out, int N) {
  __shared__ __align__(16) unsigned short WO[64 * 72];
  __shared__ __align__(16) float BO[64];
  int t = threadIdx.x;
  int lane = t & 63, wv = t >> 6;
  int nl = lane & 15, q = lane >> 4;
  int w16 = wv * 16;
  int n0g = blockIdx.x * 64;

  {
    const uint4* s4 = (const uint4*)(wt + 7 * 4608);  // matrix 7 = W_out
    uint4* d4 = (uint4*)WO;
#pragma unroll
    for (int i = 0; i < 3; ++i) {
      int idx = i * 256 + t;
      if (idx < 576) d4[idx] = s4[idx];
    }
  }
  if (t < 64) BO[t] = b[t];

  int row = n0g + w16 + nl;        // my node
  bf16x8 bb[2];
#pragma unroll
  for (int s = 0; s < 2; ++s) {
    union { unsigned int u[4]; bf16x8 v; } fb;
    if (row < N) {
      int kb = s * 32 + q * 8;
      float4 na = *(const float4*)(accg + (size_t)row * 64 + kb);
      float4 nb = *(const float4*)(accg + (size_t)row * 64 + kb + 4);
      float4 da = *(const float4*)(sg + (size_t)row * 64 + kb);
      float4 db = *(const float4*)(sg + (size_t)row * 64 + kb + 4);
      fb.u[0] = cvt_pk_bf16(na.x / (da.x + 1e-16f), na.y / (da.y + 1e-16f));
      fb.u[1] = cvt_pk_bf16(na.z / (da.z + 1e-16f), na.w / (da.w + 1e-16f));
      fb.u[2] = cvt_pk_bf16(nb.x / (db.x + 1e-16f), nb.y / (db.y + 1e-16f));
      fb.u[3] = cvt_pk_bf16(nb.z / (db.z + 1e-16f), nb.w / (db.w + 1e-16f));
    } else {
#pragma unroll
      for (int j = 0; j < 4; ++j) fb.u[j] = 0;
    }
    bb[s] = fb.v;
  }
  __syncthreads();

  bool g = row < N;
#pragma unroll
  for (int m0 = 0; m0 < 4; ++m0) {
    f32x4 acc = *(const f32x4*)&BO[m0 * 16 + q * 4];
    acc = __builtin_amdgcn_mfma_f32_16x16x32_bf16(
        ld_bf8(&WO[(m0 * 16 + nl) * 72 + q * 8]), bb[0], acc, 0, 0, 0);
    acc = __builtin_amdgcn_mfma_f32_16x16x32_bf16(
        ld_bf8(&WO[(m0 * 16 + nl) * 72 + 32 + q * 8]), bb[1], acc, 0, 0, 0);
    if (g) {
      float4 o;
      o.x = fmaxf(acc[0], 0.f);
      o.y = fmaxf(acc[1], 0.f);
      o.z = fmaxf(acc[2], 0.f);
      o.w = fmaxf(acc[3], 0.f);
      *(float4*)(out + (size_t)row * 64 + m0 * 16 + q * 4) = o;
    }
  }
}

// ------------------------------- launcher ----------------------------------

extern "C" void kernel_launch(void* const* d_in, const int* in_sizes, int n_in,
                              void* d_out, int out_size, void* d_ws, size_t ws_size,
                              hipStream_t stream) {
  const float* x     = (const float*)d_in[0];
  const float* pos   = (const float*)d_in[1];
  const int*   eidx  = (const int*)d_in[2];
  const float* W_in  = (const float*)d_in[3];
  const float* b_in  = (const float*)d_in[4];
  const float* ln_g  = (const float*)d_in[5];
  const float* ln_b  = (const float*)d_in[6];
  const float* W_lin = (const float*)d_in[7];
  const float* W_src = (const float*)d_in[8];
  const float* W_dst = (const float*)d_in[9];
  const float* pn_W1 = (const float*)d_in[10];
  const float* pn_b1 = (const float*)d_in[11];
  const float* pn_W2 = (const float*)d_in[12];
  const float* pn_b2 = (const float*)d_in[13];
  const float* an_W1 = (const float*)d_in[14];
  const float* an_b1 = (const float*)d_in[15];
  const float* an_W2 = (const float*)d_in[16];
  const float* an_b2 = (const float*)d_in[17];
  const float* W_out = (const float*)d_in[18];
  const float* b_out = (const float*)d_in[19];
  float* out = (float*)d_out;

  int N = in_sizes[0] / 64;
  int E = in_sizes[2] / 2;
  const int* src = eidx;
  const int* dst = eidx + E;

  char* w = (char*)d_ws;
  auto alloc = [&](size_t bytes) -> void* {
    void* p = (void*)w;
    w += (bytes + 255) & ~(size_t)255;
    return p;
  };
  unsigned short* qg = (unsigned short*)alloc((size_t)N * 64 * 2);
  unsigned short* kg = (unsigned short*)alloc((size_t)N * 64 * 2);
  unsigned short* vg = (unsigned short*)alloc((size_t)N * 64 * 2);
  float* sg   = (float*)alloc((size_t)N * 64 * 4);
  float* accg = (float*)alloc((size_t)N * 64 * 4);   // contiguous after sg
  int2* spair = (int2*)alloc((size_t)E * 8);
  unsigned short* wt = (unsigned short*)alloc(8 * 4608 * 2);
  int* hist   = (int*)alloc((size_t)N * 4);
  int* cursor = (int*)alloc((size_t)N * 4);
  int* bsum   = (int*)alloc(1024 * 4);
  int* incl   = (int*)accg;   // scan scratch aliased into accg (used first)

  int nb1 = (N + 1023) / 1024;               // <= 256 required by k_scan3
  int nodeBlocks = (N + 63) / 64;
  int histBlocks = (E + 255) / 256;
  int zcount = N * 32;                        // sg+accg in float4s
  int zBlocks = (zcount + 255) / 256;
  int numTiles = (E + 63) / 64;
  int edgeGrid = numTiles < 1024 ? numTiles : 1024;  // 4 blocks/CU x 256 CU

  hipMemsetAsync(hist, 0, (size_t)N * 4, stream);
  k_prep_hist<<<8 + histBlocks, 256, 0, stream>>>(
      W_in, W_dst, W_src, W_lin, pn_W2, an_W1, an_W2, W_out, wt, dst, hist, E);
  k_node<<<nodeBlocks + nb1, 256, 0, stream>>>(
      x, wt, b_in, ln_g, ln_b, qg, kg, vg, N, hist, incl, bsum, nodeBlocks);
  k_scan3<<<nb1, 256, 0, stream>>>(incl, hist, bsum, cursor, N);
  k_scatter_zero<<<histBlocks + zBlocks, 256, 0, stream>>>(
      src, dst, cursor, spair, E, (float4*)sg, zcount, histBlocks);
  k_edge<<<edgeGrid, 256, 0, stream>>>(spair, pos, qg, kg, vg, wt,
                                       pn_W1, pn_b1, pn_b2, an_b1, an_b2,
                                       sg, accg, E, numTiles);
  k_out<<<nodeBlocks, 256, 0, stream>>>(accg, sg, wt, b_out, out, N);
}

// Round 9
// 497.132 us; speedup vs baseline: 1.1708x; 1.1708x over previous
//
#include <hip/hip_runtime.h>

// ---------------------------------------------------------------------------
// PointTransformerBlock, MI355X.  R21 = R17 (last passing, 510us) + v-permute:
//  R19/R20 pipeline arc abandoned (two independent implementations failed
//  correctness identically; unexplained -> banked).  R21 is a MINIMAL diff
//  from R17 attacking gather transaction granularity:
//  - vg stored PERMUTED: pos(c)=q*16+m0*4+r for c=m0*16+q*4+r (free index
//    change in k_node's v-store).  k_edge lane then reads its 16 v-elems as
//    ONE contiguous 32B (2x ld_bf8); 4 q-lanes/edge cover the 128B row
//    contiguously -> 2x64B wave transactions (was 4x32B).  Random-row
//    transactions/edge: 6 -> 4 (k:2x64B already optimal; q L2-hot).
//  - pay-overwrite indexes vlo/vhi statically ((m0&1)*4+r).
//  Everything else byte-identical to R17: transposed GEMMs, an_W2 in regs,
//  pay-fused SD, reg-resident tile state, zero per-tile barriers,
//  launch_bounds(256,4), grid 1024, LDS 38.9KB.
//  MFMA layouts (HW-verified, guide §3): A[m=lane&15][k=q*8+j],
//  B[k=q*8+j][n=lane&15], C/D col=lane&15 row=q*4+r.
// ---------------------------------------------------------------------------

typedef __bf16 bf16x8 __attribute__((ext_vector_type(8)));
typedef float f32x4 __attribute__((ext_vector_type(4)));

__device__ inline unsigned short f2bf(float f) {
  return __builtin_bit_cast(unsigned short, (__bf16)f);   // v_cvt (RNE)
}
__device__ inline float bf2f(unsigned short s) {
  return __uint_as_float(((unsigned int)s) << 16);
}
__device__ inline bf16x8 ld_bf8(const unsigned short* p) {
  union { uint4 i; bf16x8 v; } u;
  u.i = *(const uint4*)p;
  return u.v;
}
// packed f32->2xbf16 (gfx950; no builtin -- guide T12/m240). dst.lo=cvt(lo).
__device__ inline unsigned int cvt_pk_bf16(float lo, float hi) {
  unsigned int r;
  asm("v_cvt_pk_bf16_f32 %0, %1, %2" : "=v"(r) : "v"(lo), "v"(hi));
  return r;
}

// --------------------- prep kernel with fused histogram --------------------

__global__ __launch_bounds__(256) void k_prep_hist(
    const float* __restrict__ W_in, const float* __restrict__ W_dst,
    const float* __restrict__ W_src, const float* __restrict__ W_lin,
    const float* __restrict__ pn_W2, const float* __restrict__ an_W1,
    const float* __restrict__ an_W2, const float* __restrict__ W_out,
    unsigned short* __restrict__ wt,
    const int* __restrict__ dst, int* __restrict__ hist, int E) {
  int t = threadIdx.x;
  if (blockIdx.x >= 8) {
    int e = (blockIdx.x - 8) * 256 + t;
    if (e < E) atomicAdd(&hist[dst[e]], 1);
    return;
  }
  const float* Ws[8] = {W_in, W_dst, W_src, W_lin, pn_W2, an_W1, an_W2, W_out};
  const float* W = Ws[blockIdx.x];
  unsigned short* o = wt + (size_t)blockIdx.x * 4608;
#pragma unroll
  for (int i = 0; i < 16; ++i) {
    int e = i * 256 + t;           // e = k*64 + n  (coalesced read)
    int k = e >> 6, n = e & 63;
    o[n * 72 + k] = f2bf(W[e]);    // wt[n][k] = W^T[n][k]
  }
}

// ------------------------------ sort kernels -------------------------------

// scan3 with inline block-offset: reduce bsum[0..blockIdx) in-block.
// Requires gridDim <= 256 (N <= 262144).
__global__ __launch_bounds__(256) void k_scan3(
    const int* __restrict__ incl, const int* __restrict__ hist,
    const int* __restrict__ bsum, int* __restrict__ cursor, int N) {
  __shared__ int red[256];
  int t = threadIdx.x;
  red[t] = (t < (int)blockIdx.x) ? bsum[t] : 0;
  __syncthreads();
#pragma unroll
  for (int off = 128; off; off >>= 1) {
    if (t < off) red[t] += red[t + off];
    __syncthreads();
  }
  int bo = red[0];
  int base = blockIdx.x * 1024 + t * 4;
#pragma unroll
  for (int i = 0; i < 4; ++i) {
    int id = base + i;
    if (id < N) cursor[id] = bo + incl[id] - hist[id];
  }
}

// scatter with fused sg/accg zeroing (sibling blocks).
__global__ void k_scatter_zero(const int* __restrict__ src,
                               const int* __restrict__ dst,
                               int* __restrict__ cursor,
                               int2* __restrict__ spair, int E,
                               float4* __restrict__ zbase, int zcount,
                               int scatterBlocks) {
  int t = threadIdx.x;
  if ((int)blockIdx.x >= scatterBlocks) {
    int i = ((int)blockIdx.x - scatterBlocks) * 256 + t;
    if (i < zcount) zbase[i] = make_float4(0.f, 0.f, 0.f, 0.f);
    return;
  }
  int e = blockIdx.x * 256 + t;
  if (e < E) {
    int s = src[e], d = dst[e];
    int p = atomicAdd(&cursor[d], 1);
    spair[p] = make_int2(s, d);
  }
}

// ---------------- node kernel (transposed MFMA) with fused scan1 -----------

__global__ __launch_bounds__(256) void k_node(
    const float* __restrict__ x, const unsigned short* __restrict__ wt,
    const float* __restrict__ b_in, const float* __restrict__ ln_g,
    const float* __restrict__ ln_b,
    unsigned short* __restrict__ qg, unsigned short* __restrict__ kg,
    unsigned short* __restrict__ vg,
    int N, const int* __restrict__ hist, int* __restrict__ incl,
    int* __restrict__ bsum, int nodeBlocks) {
  int t = threadIdx.x;

  // ---- fused scan1 blocks ----
  if ((int)blockIdx.x >= nodeBlocks) {
    __shared__ int sd[256];
    int bid = blockIdx.x - nodeBlocks;
    int base = bid * 1024 + t * 4;
    int v[4]; int ts = 0;
#pragma unroll
    for (int i = 0; i < 4; ++i) {
      int idx = base + i;
      v[i] = (idx < N) ? hist[idx] : 0;
      ts += v[i];
    }
    sd[t] = ts;
    __syncthreads();
    for (int off = 1; off < 256; off <<= 1) {
      int xv = (t >= off) ? sd[t - off] : 0;
      __syncthreads();
      sd[t] += xv;
      __syncthreads();
    }
    int run = sd[t] - ts;
#pragma unroll
    for (int i = 0; i < 4; ++i) {
      run += v[i];
      int idx = base + i;
      if (idx < N) incl[idx] = run;
    }
    if (t == 255) bsum[bid] = sd[255];
    return;
  }

  __shared__ __align__(16) unsigned short WALL[4 * 64 * 72];
  __shared__ __align__(16) unsigned short HT[64 * 72];   // h [node][ch]
  __shared__ __align__(16) float LNG[64], LNB[64], BIN[64];

  int lane = t & 63, wv = t >> 6;
  int nl = lane & 15, q = lane >> 4;
  int w16 = wv * 16;
  int n0g = blockIdx.x * 64;

  {
    const uint4* s4 = (const uint4*)wt;
    uint4* d4 = (uint4*)WALL;
#pragma unroll
    for (int i = 0; i < 9; ++i) d4[i * 256 + t] = s4[i * 256 + t];
  }
  if (t < 64) { LNG[t] = ln_g[t]; LNB[t] = ln_b[t]; BIN[t] = b_in[t]; }

  int row = n0g + w16 + nl;        // my node
  bf16x8 b[2];                     // B-frag: x[node=nl][k]
#pragma unroll
  for (int s = 0; s < 2; ++s) {
    union { unsigned int u[4]; bf16x8 v; } fb;
    if (row < N) {
      int kb = s * 32 + q * 8;
      float4 xa = *(const float4*)(x + (size_t)row * 64 + kb);
      float4 xb = *(const float4*)(x + (size_t)row * 64 + kb + 4);
      fb.u[0] = cvt_pk_bf16(xa.x, xa.y);
      fb.u[1] = cvt_pk_bf16(xa.z, xa.w);
      fb.u[2] = cvt_pk_bf16(xb.x, xb.y);
      fb.u[3] = cvt_pk_bf16(xb.z, xb.w);
    } else {
#pragma unroll
      for (int j = 0; j < 4; ++j) fb.u[j] = 0;
    }
    b[s] = fb.v;
  }
  __syncthreads();

  // GEMM1: h = relu(x @ W_in + b_in); lane holds ch m0*16+q*4+r of node nl
  f32x4 h[4];
#pragma unroll
  for (int m0 = 0; m0 < 4; ++m0) {
    f32x4 acc = *(const f32x4*)&BIN[m0 * 16 + q * 4];
    acc = __builtin_amdgcn_mfma_f32_16x16x32_bf16(
        ld_bf8(&WALL[(m0 * 16 + nl) * 72 + q * 8]), b[0], acc, 0, 0, 0);
    acc = __builtin_amdgcn_mfma_f32_16x16x32_bf16(
        ld_bf8(&WALL[(m0 * 16 + nl) * 72 + 32 + q * 8]), b[1], acc, 0, 0, 0);
#pragma unroll
    for (int r = 0; r < 4; ++r) acc[r] = fmaxf(acc[r], 0.f);
    h[m0] = acc;
  }

  // LayerNorm over channels of node nl: local 16 + reduce across q-lanes
  float sv = 0.f, sq = 0.f;
#pragma unroll
  for (int m0 = 0; m0 < 4; ++m0)
#pragma unroll
    for (int r = 0; r < 4; ++r) {
      float v = h[m0][r];
      sv += v; sq += v * v;
    }
  sv += __shfl_xor(sv, 16); sq += __shfl_xor(sq, 16);
  sv += __shfl_xor(sv, 32); sq += __shfl_xor(sq, 32);
  float mu = sv * (1.f / 64.f);
  float var = sq * (1.f / 64.f) - mu * mu;
  float rs = rsqrtf(var + 1e-5f);
#pragma unroll
  for (int m0 = 0; m0 < 4; ++m0) {
    f32x4 g4 = *(const f32x4*)&LNG[m0 * 16 + q * 4];
    f32x4 o4 = *(const f32x4*)&LNB[m0 * 16 + q * 4];
    float v0 = (h[m0][0] - mu) * rs * g4[0] + o4[0];
    float v1 = (h[m0][1] - mu) * rs * g4[1] + o4[1];
    float v2 = (h[m0][2] - mu) * rs * g4[2] + o4[2];
    float v3 = (h[m0][3] - mu) * rs * g4[3] + o4[3];
    uint2 pk;
    pk.x = cvt_pk_bf16(v0, v1);
    pk.y = cvt_pk_bf16(v2, v3);
    *(uint2*)&HT[(w16 + nl) * 72 + m0 * 16 + q * 4] = pk;
  }

  b[0] = ld_bf8(&HT[(w16 + nl) * 72 + q * 8]);
  b[1] = ld_bf8(&HT[(w16 + nl) * 72 + 32 + q * 8]);

  unsigned short* Og[3] = {qg, kg, vg};
  bool g = row < N;
#pragma unroll
  for (int m = 0; m < 3; ++m) {
    const unsigned short* Wm = WALL + (m + 1) * 4608;
#pragma unroll
    for (int m0 = 0; m0 < 4; ++m0) {
      f32x4 acc = {0.f, 0.f, 0.f, 0.f};
      acc = __builtin_amdgcn_mfma_f32_16x16x32_bf16(
          ld_bf8(&Wm[(m0 * 16 + nl) * 72 + q * 8]), b[0], acc, 0, 0, 0);
      acc = __builtin_amdgcn_mfma_f32_16x16x32_bf16(
          ld_bf8(&Wm[(m0 * 16 + nl) * 72 + 32 + q * 8]), b[1], acc, 0, 0, 0);
      if (g) {
        uint2 pk;
        pk.x = cvt_pk_bf16(acc[0], acc[1]);
        pk.y = cvt_pk_bf16(acc[2], acc[3]);
        // v (m==2) stored PERMUTED: pos(c)=q*16+m0*4+r so a k_edge lane
        // reads its 16 v-elems as one contiguous 32B block.  q/k unchanged.
        int off = (m == 2) ? (q * 16 + m0 * 4) : (m0 * 16 + q * 4);
        *(uint2*)(Og[m] + (size_t)row * 64 + off) = pk;
      }
    }
  }
}

// ---- edge kernel (persistent, 4 blocks/CU, reg weights, pay-fused SD) -----

__global__ __launch_bounds__(256, 4) void k_edge(
    const int2* __restrict__ spair, const float* __restrict__ pos,
    const unsigned short* __restrict__ qg, const unsigned short* __restrict__ kg,
    const unsigned short* __restrict__ vg,
    const unsigned short* __restrict__ wt,
    const float* __restrict__ pn_W1, const float* __restrict__ pn_b1,
    const float* __restrict__ pn_b2,
    const float* __restrict__ an_b1, const float* __restrict__ an_b2,
    float* __restrict__ sg, float* __restrict__ accg, int E, int numTiles) {
  __shared__ __align__(16) unsigned short WAB[2 * 64 * 72];  // pn_W2 | an_W1
  __shared__ __align__(16) unsigned short SD[64 * 72];   // delta, then pay
  __shared__ __align__(16) unsigned short SB[64 * 72];   // a1, then ex
  __shared__ float W1[3 * 64];
  __shared__ float B1[64];
  __shared__ __align__(16) float B2[64], AB1[64], AB2[64];

  int t = threadIdx.x;
  int lane = t & 63, wv = t >> 6;
  int nl = lane & 15, q = lane >> 4;
  int w16 = wv * 16;

  // ---- one-time staging: pn_W2 + an_W1 to LDS (uint4 memcpy) ----
  {
    const uint4* s4 = (const uint4*)(wt + 4 * 4608);  // matrices 4,5
    uint4* d4 = (uint4*)WAB;
#pragma unroll
    for (int i = 0; i < 5; ++i) {
      int idx = i * 256 + t;
      if (idx < 1152) d4[idx] = s4[idx];
    }
  }
  if (t < 192) W1[t] = pn_W1[t];
  if (t < 64) {
    B1[t] = pn_b1[t];  B2[t] = pn_b2[t];
    AB1[t] = an_b1[t]; AB2[t] = an_b2[t];
  }
  // ---- an_W2 A-frags -> registers (32 VGPR), straight from wt ----
  bf16x8 wan2r[8];
#pragma unroll
  for (int m0 = 0; m0 < 4; ++m0)
#pragma unroll
    for (int s = 0; s < 2; ++s)
      wan2r[m0 * 2 + s] =
          ld_bf8(wt + 6 * 4608 + (m0 * 16 + nl) * 72 + s * 32 + q * 8);
  const unsigned short* WPN2 = WAB;
  const unsigned short* WAN1 = WAB + 4608;
  __syncthreads();   // the ONLY barrier: weights/biases visible to all waves

  // Lane L of wave wv owns edge e0 + w16 + (L&15): its (src,dst) pair "my"
  // IS the tile's cross-lane state (distributed via __shfl, no LDS, no
  // barriers; SD/SB strips rows w16..w16+15 stay wave-private).
  long er_off = w16 + nl;
  int2 my;
  {
    long er = (long)blockIdx.x * 64 + er_off;
    my = (er < E) ? spair[er] : make_int2(0, 0);
  }

  for (int tile = blockIdx.x; tile < numTiles; tile += gridDim.x) {
    long e0 = (long)tile * 64;

    // ---- tile-top fan-out: all gathers issue off prefetched "my" ----
    const unsigned short* qr = qg + (size_t)my.y * 64;
    const unsigned short* kr = kg + (size_t)my.x * 64;
    bf16x8 qf[2], kf[2];
#pragma unroll
    for (int s = 0; s < 2; ++s) {
      int kb = s * 32 + q * 8;
      qf[s] = ld_bf8(qr + kb);
      kf[s] = ld_bf8(kr + kb);
    }
    // v for my OWN edge's src: PERMUTED layout -> one contiguous 32B
    // (vlo = elems m0=0,1; vhi = elems m0=2,3; element (m0&1)*4+r)
    const unsigned short* vr = vg + (size_t)my.x * 64;
    bf16x8 vlo = ld_bf8(vr + q * 16);
    bf16x8 vhi = ld_bf8(vr + q * 16 + 8);
    // pos diffs for my own edge (strip row w16+nl == my edge)
    float p0 = pos[my.y * 3 + 0] - pos[my.x * 3 + 0];
    float p1 = pos[my.y * 3 + 1] - pos[my.x * 3 + 1];
    float p2 = pos[my.y * 3 + 2] - pos[my.x * 3 + 2];

    // ---- prefetch next tile's spair into regs (hide under compute) ----
    int2 nxt = make_int2(0, 0);
    {
      long ntile = (long)tile + gridDim.x;
      if (ntile < numTiles) {
        long ner = ntile * 64 + er_off;
        nxt = (ner < E) ? spair[ner] : make_int2(0, 0);
      }
    }

    bool elive = (e0 + er_off) < E;   // my edge's liveness (col = nl)

    bf16x8 b[2];

    // ---- pos-MLP layer1 (K=3) straight into B-frag registers ----
#pragma unroll
    for (int s = 0; s < 2; ++s) {
      union { unsigned int u[4]; bf16x8 v; } fb;
      int kb = s * 32 + q * 8;
#pragma unroll
      for (int jj = 0; jj < 4; ++jj) {
        int c0 = kb + 2 * jj, c1 = c0 + 1;
        float v0 = fmaf(p0, W1[c0],
                   fmaf(p1, W1[64 + c0],
                   fmaf(p2, W1[128 + c0], B1[c0])));
        float v1 = fmaf(p0, W1[c1],
                   fmaf(p1, W1[64 + c1],
                   fmaf(p2, W1[128 + c1], B1[c1])));
        fb.u[jj] = cvt_pk_bf16(fmaxf(v0, 0.f), fmaxf(v1, 0.f));
      }
      b[s] = fb.v;
    }

    // ---- GEMM1: delta^T = pn_W2^T @ A1^T, bias-in-acc, relu -> SD ----
    // keep delta f32 in regs (dlt) for the pay overwrite below
    f32x4 dlt[4];
#pragma unroll
    for (int m0 = 0; m0 < 4; ++m0) {
      f32x4 acc = *(const f32x4*)&B2[m0 * 16 + q * 4];
      acc = __builtin_amdgcn_mfma_f32_16x16x32_bf16(
          ld_bf8(&WPN2[(m0 * 16 + nl) * 72 + q * 8]), b[0], acc, 0, 0, 0);
      acc = __builtin_amdgcn_mfma_f32_16x16x32_bf16(
          ld_bf8(&WPN2[(m0 * 16 + nl) * 72 + 32 + q * 8]), b[1], acc, 0, 0, 0);
#pragma unroll
      for (int r = 0; r < 4; ++r) acc[r] = fmaxf(acc[r], 0.f);
      dlt[m0] = acc;
      uint2 pk;
      pk.x = cvt_pk_bf16(acc[0], acc[1]);
      pk.y = cvt_pk_bf16(acc[2], acc[3]);
      *(uint2*)&SD[(w16 + nl) * 72 + m0 * 16 + q * 4] = pk;
    }

    // ---- build ai = q[dst]-k[src]+delta in B-frag layout (reads SD) ----
#pragma unroll
    for (int s = 0; s < 2; ++s) {
      int kb = s * 32 + q * 8;
      bf16x8 d8 = ld_bf8(&SD[(w16 + nl) * 72 + kb]);
      union { unsigned int u[4]; bf16x8 v; } fb;
#pragma unroll
      for (int jj = 0; jj < 4; ++jj) {
        float v0 = (float)qf[s][2 * jj]     - (float)kf[s][2 * jj]     + (float)d8[2 * jj];
        float v1 = (float)qf[s][2 * jj + 1] - (float)kf[s][2 * jj + 1] + (float)d8[2 * jj + 1];
        fb.u[jj] = cvt_pk_bf16(v0, v1);
      }
      b[s] = fb.v;
    }

    // ---- overwrite SD with pay = delta + v[src]  (same-wave DS order:
    //      the ai-build reads above are issued before these writes) ----
#pragma unroll
    for (int m0 = 0; m0 < 4; ++m0) {
      float va0, va1, va2, va3;
      if (m0 == 0)      { va0 = (float)vlo[0]; va1 = (float)vlo[1];
                          va2 = (float)vlo[2]; va3 = (float)vlo[3]; }
      else if (m0 == 1) { va0 = (float)vlo[4]; va1 = (float)vlo[5];
                          va2 = (float)vlo[6]; va3 = (float)vlo[7]; }
      else if (m0 == 2) { va0 = (float)vhi[0]; va1 = (float)vhi[1];
                          va2 = (float)vhi[2]; va3 = (float)vhi[3]; }
      else              { va0 = (float)vhi[4]; va1 = (float)vhi[5];
                          va2 = (float)vhi[6]; va3 = (float)vhi[7]; }
      uint2 pk;
      pk.x = cvt_pk_bf16(dlt[m0][0] + va0, dlt[m0][1] + va1);
      pk.y = cvt_pk_bf16(dlt[m0][2] + va2, dlt[m0][3] + va3);
      *(uint2*)&SD[(w16 + nl) * 72 + m0 * 16 + q * 4] = pk;
    }

    // ---- GEMM2: a1^T = an_W1^T @ ai^T, bias-in-acc, relu -> SB ----
#pragma unroll
    for (int m0 = 0; m0 < 4; ++m0) {
      f32x4 acc = *(const f32x4*)&AB1[m0 * 16 + q * 4];
      acc = __builtin_amdgcn_mfma_f32_16x16x32_bf16(
          ld_bf8(&WAN1[(m0 * 16 + nl) * 72 + q * 8]), b[0], acc, 0, 0, 0);
      acc = __builtin_amdgcn_mfma_f32_16x16x32_bf16(
          ld_bf8(&WAN1[(m0 * 16 + nl) * 72 + 32 + q * 8]), b[1], acc, 0, 0, 0);
      uint2 pk;
      pk.x = cvt_pk_bf16(fmaxf(acc[0], 0.f), fmaxf(acc[1], 0.f));
      pk.y = cvt_pk_bf16(fmaxf(acc[2], 0.f), fmaxf(acc[3], 0.f));
      *(uint2*)&SB[(w16 + nl) * 72 + m0 * 16 + q * 4] = pk;
    }

    // ---- GEMM3: alpha^T = an_W2^T(regs) @ a1^T; ex = exp(relu) -> SB ----
    // (wave-private SB rows; DS ops in-order per wave, no barrier needed)
    b[0] = ld_bf8(&SB[(w16 + nl) * 72 + q * 8]);
    b[1] = ld_bf8(&SB[(w16 + nl) * 72 + 32 + q * 8]);
#pragma unroll
    for (int m0 = 0; m0 < 4; ++m0) {
      f32x4 acc = *(const f32x4*)&AB2[m0 * 16 + q * 4];
      acc = __builtin_amdgcn_mfma_f32_16x16x32_bf16(
          wan2r[m0 * 2 + 0], b[0], acc, 0, 0, 0);
      acc = __builtin_amdgcn_mfma_f32_16x16x32_bf16(
          wan2r[m0 * 2 + 1], b[1], acc, 0, 0, 0);
      float e0v = elive ? __expf(fmaxf(acc[0], 0.f)) : 0.f;
      float e1v = elive ? __expf(fmaxf(acc[1], 0.f)) : 0.f;
      float e2v = elive ? __expf(fmaxf(acc[2], 0.f)) : 0.f;
      float e3v = elive ? __expf(fmaxf(acc[3], 0.f)) : 0.f;
      uint2 pk;
      pk.x = cvt_pk_bf16(e0v, e1v);
      pk.y = cvt_pk_bf16(e2v, e3v);
      *(uint2*)&SB[(w16 + nl) * 72 + m0 * 16 + q * 4] = pk;
    }

    // ---- segmented per-dst-run reduction (dst runs via shuffle) ----
    {
      int c = lane;
      int cur = __shfl(my.y, 0);
      float ssum = 0.f, asum = 0.f;
#pragma unroll
      for (int i = 0; i < 16; ++i) {
        int d = __shfl(my.y, i);
        if (d != cur) {
          if (ssum != 0.f) {
            atomicAdd(&sg[(size_t)cur * 64 + c], ssum);
            atomicAdd(&accg[(size_t)cur * 64 + c], asum);
          }
          cur = d; ssum = 0.f; asum = 0.f;
        }
        float ex = bf2f(SB[(w16 + i) * 72 + c]);
        float pay = bf2f(SD[(w16 + i) * 72 + c]);   // pay = delta + v
        ssum += ex;
        asum = fmaf(ex, pay, asum);
      }
      if (ssum != 0.f) {
        atomicAdd(&sg[(size_t)cur * 64 + c], ssum);
        atomicAdd(&accg[(size_t)cur * 64 + c], asum);
      }
    }

    my = nxt;   // rotate prefetched pair
  }
}

// ------------------------- out kernel (transposed MFMA) --------------------

__global__ __launch_bounds__(256) void k_out(const float* __restrict__ accg,
                                             const float* __restrict__ sg,
                                             const unsigned short* __restrict__ wt,
                                             const float* __restrict__ b,
                                             float* __restrict__ out, int N) {
  __shared__ __align__(16) unsigned short WO[64 * 72];
  __shared__ __align__(16) float BO[64];
  int t = threadIdx.x;
  int lane = t & 63, wv = t >> 6;
  int nl = lane & 15, q = lane >> 4;
  int w16 = wv * 16;
  int n0g = blockIdx.x * 64;

  {
    const uint4* s4 = (const uint4*)(wt + 7 * 4608);  // matrix 7 = W_out
    uint4* d4 = (uint4*)WO;
#pragma unroll
    for (int i = 0; i < 3; ++i) {
      int idx = i * 256 + t;
      if (idx < 576) d4[idx] = s4[idx];
    }
  }
  if (t < 64) BO[t] = b[t];

  int row = n0g + w16 + nl;        // my node
  bf16x8 bb[2];
#pragma unroll
  for (int s = 0; s < 2; ++s) {
    union { unsigned int u[4]; bf16x8 v; } fb;
    if (row < N) {
      int kb = s * 32 + q * 8;
      float4 na = *(const float4*)(accg + (size_t)row * 64 + kb);
      float4 nb = *(const float4*)(accg + (size_t)row * 64 + kb + 4);
      float4 da = *(const float4*)(sg + (size_t)row * 64 + kb);
      float4 db = *(const float4*)(sg + (size_t)row * 64 + kb + 4);
      fb.u[0] = cvt_pk_bf16(na.x / (da.x + 1e-16f), na.y / (da.y + 1e-16f));
      fb.u[1] = cvt_pk_bf16(na.z / (da.z + 1e-16f), na.w / (da.w + 1e-16f));
      fb.u[2] = cvt_pk_bf16(nb.x / (db.x + 1e-16f), nb.y / (db.y + 1e-16f));
      fb.u[3] = cvt_pk_bf16(nb.z / (db.z + 1e-16f), nb.w / (db.w + 1e-16f));
    } else {
#pragma unroll
      for (int j = 0; j < 4; ++j) fb.u[j] = 0;
    }
    bb[s] = fb.v;
  }
  __syncthreads();

  bool g = row < N;
#pragma unroll
  for (int m0 = 0; m0 < 4; ++m0) {
    f32x4 acc = *(const f32x4*)&BO[m0 * 16 + q * 4];
    acc = __builtin_amdgcn_mfma_f32_16x16x32_bf16(
        ld_bf8(&WO[(m0 * 16 + nl) * 72 + q * 8]), bb[0], acc, 0, 0, 0);
    acc = __builtin_amdgcn_mfma_f32_16x16x32_bf16(
        ld_bf8(&WO[(m0 * 16 + nl) * 72 + 32 + q * 8]), bb[1], acc, 0, 0, 0);
    if (g) {
      float4 o;
      o.x = fmaxf(acc[0], 0.f);
      o.y = fmaxf(acc[1], 0.f);
      o.z = fmaxf(acc[2], 0.f);
      o.w = fmaxf(acc[3], 0.f);
      *(float4*)(out + (size_t)row * 64 + m0 * 16 + q * 4) = o;
    }
  }
}

// ------------------------------- launcher ----------------------------------

extern "C" void kernel_launch(void* const* d_in, const int* in_sizes, int n_in,
                              void* d_out, int out_size, void* d_ws, size_t ws_size,
                              hipStream_t stream) {
  const float* x     = (const float*)d_in[0];
  const float* pos   = (const float*)d_in[1];
  const int*   eidx  = (const int*)d_in[2];
  const float* W_in  = (const float*)d_in[3];
  const float* b_in  = (const float*)d_in[4];
  const float* ln_g  = (const float*)d_in[5];
  const float* ln_b  = (const float*)d_in[6];
  const float* W_lin = (const float*)d_in[7];
  const float* W_src = (const float*)d_in[8];
  const float* W_dst = (const float*)d_in[9];
  const float* pn_W1 = (const float*)d_in[10];
  const float* pn_b1 = (const float*)d_in[11];
  const float* pn_W2 = (const float*)d_in[12];
  const float* pn_b2 = (const float*)d_in[13];
  const float* an_W1 = (const float*)d_in[14];
  const float* an_b1 = (const float*)d_in[15];
  const float* an_W2 = (const float*)d_in[16];
  const float* an_b2 = (const float*)d_in[17];
  const float* W_out = (const float*)d_in[18];
  const float* b_out = (const float*)d_in[19];
  float* out = (float*)d_out;

  int N = in_sizes[0] / 64;
  int E = in_sizes[2] / 2;
  const int* src = eidx;
  const int* dst = eidx + E;

  char* w = (char*)d_ws;
  auto alloc = [&](size_t bytes) -> void* {
    void* p = (void*)w;
    w += (bytes + 255) & ~(size_t)255;
    return p;
  };
  unsigned short* qg = (unsigned short*)alloc((size_t)N * 64 * 2);
  unsigned short* kg = (unsigned short*)alloc((size_t)N * 64 * 2);
  unsigned short* vg = (unsigned short*)alloc((size_t)N * 64 * 2);
  float* sg   = (float*)alloc((size_t)N * 64 * 4);
  float* accg = (float*)alloc((size_t)N * 64 * 4);   // contiguous after sg
  int2* spair = (int2*)alloc((size_t)E * 8);
  unsigned short* wt = (unsigned short*)alloc(8 * 4608 * 2);
  int* hist   = (int*)alloc((size_t)N * 4);
  int* cursor = (int*)alloc((size_t)N * 4);
  int* bsum   = (int*)alloc(1024 * 4);
  int* incl   = (int*)accg;   // scan scratch aliased into accg (used first)

  int nb1 = (N + 1023) / 1024;               // <= 256 required by k_scan3
  int nodeBlocks = (N + 63) / 64;
  int histBlocks = (E + 255) / 256;
  int zcount = N * 32;                        // sg+accg in float4s
  int zBlocks = (zcount + 255) / 256;
  int numTiles = (E + 63) / 64;
  int edgeGrid = numTiles < 1024 ? numTiles : 1024;  // 4 blocks/CU x 256 CU

  hipMemsetAsync(hist, 0, (size_t)N * 4, stream);
  k_prep_hist<<<8 + histBlocks, 256, 0, stream>>>(
      W_in, W_dst, W_src, W_lin, pn_W2, an_W1, an_W2, W_out, wt, dst, hist, E);
  k_node<<<nodeBlocks + nb1, 256, 0, stream>>>(
      x, wt, b_in, ln_g, ln_b, qg, kg, vg, N, hist, incl, bsum, nodeBlocks);
  k_scan3<<<nb1, 256, 0, stream>>>(incl, hist, bsum, cursor, N);
  k_scatter_zero<<<histBlocks + zBlocks, 256, 0, stream>>>(
      src, dst, cursor, spair, E, (float4*)sg, zcount, histBlocks);
  k_edge<<<edgeGrid, 256, 0, stream>>>(spair, pos, qg, kg, vg, wt,
                                       pn_W1, pn_b1, pn_b2, an_b1, an_b2,
                                       sg, accg, E, numTiles);
  k_out<<<nodeBlocks, 256, 0, stream>>>(accg, sg, wt, b_out, out, N);
}